// Round 1
// baseline (243.235 us; speedup 1.0000x reference)
//
#include <hip/hip_runtime.h>
#include <hip/hip_bf16.h>

// WindowAttentionRPB fused kernel, MI355X gfx950.
// Design: 1 block = 1 window (B=2048), 512 threads = 8 waves = 8 heads.
// bf16 MFMA (16x16x32) for QKV gemm, QK^T, PV, proj. fp32 softmax.
// LDS 128KB dynamic: [x 32K][q 32K][k 32K][vT 32K]; x+q reused for P.
// All row tiles XOR-swizzled: byte ^= (row&7)<<4 (kills 512B-stride conflicts).

#define TOK 64
#define CDIM 256

typedef __attribute__((ext_vector_type(8))) short short8;
typedef __attribute__((ext_vector_type(4))) float f32x4;
typedef __attribute__((ext_vector_type(4))) float float4_t;

__device__ __forceinline__ short f2bf(float f) {
  union { float f; unsigned u; } v; v.f = f;
  unsigned r = v.u + 0x7FFFu + ((v.u >> 16) & 1u);
  return (short)(r >> 16);
}

// swizzled byte address into a row-major [64][256] bf16 LDS region
__device__ __forceinline__ int rm_addr(int base, int row, int col) {
  return base + row * 512 + ((col * 2) ^ ((row & 7) << 4));
}

__global__ void preconv_kernel(const float* __restrict__ qkv_w,
                               const float* __restrict__ proj_w,
                               const float* __restrict__ rpb_table,
                               const int* __restrict__ rpb_index,
                               short* __restrict__ wqkv,
                               short* __restrict__ wproj,
                               float* __restrict__ rpb_pre) {
  int idx = blockIdx.x * blockDim.x + threadIdx.x;
  const float scale = 0.17677669529663687f; // 1/sqrt(32), folded into Wq
  if (idx < 768 * 256) {
    float v = qkv_w[idx];
    if (idx < 256 * 256) v *= scale;
    wqkv[idx] = f2bf(v);
  } else if (idx < 768 * 256 + 256 * 256) {
    int i = idx - 768 * 256;
    wproj[i] = f2bf(proj_w[i]);
  } else if (idx < 768 * 256 + 256 * 256 + 8 * 64 * 64) {
    int i = idx - (768 * 256 + 256 * 256);
    int h = i >> 12;
    int nm = i & 4095;
    rpb_pre[i] = rpb_table[rpb_index[nm] * 8 + h];
  }
}

__global__ void __launch_bounds__(512, 2) fused_attn(
    const float* __restrict__ x, const float* __restrict__ mask,
    const float* __restrict__ qkv_b, const float* __restrict__ proj_b,
    const short* __restrict__ wqkv, const short* __restrict__ wproj,
    const float* __restrict__ rpb, float* __restrict__ out) {
  extern __shared__ char smem[];
  const int b = blockIdx.x;
  const int tid = threadIdx.x;
  const int w = tid >> 6;      // wave = head
  const int lane = tid & 63;
  const int lg = lane >> 4;    // lane group 0..3
  const int ll = lane & 15;
  const float scale = 0.17677669529663687f;

  // ---- stage x -> LDS bf16 swizzled at base 0 ([64][256])
  {
    const int row = tid >> 3;
    const int c0 = (tid & 7) * 32;
    const float4_t* src = reinterpret_cast<const float4_t*>(
        x + (size_t)b * TOK * CDIM + row * CDIM + c0);
    for (int j = 0; j < 4; ++j) {
      float4_t f0 = src[2 * j];
      float4_t f1 = src[2 * j + 1];
      short8 s;
      s[0] = f2bf(f0[0]); s[1] = f2bf(f0[1]); s[2] = f2bf(f0[2]); s[3] = f2bf(f0[3]);
      s[4] = f2bf(f1[0]); s[5] = f2bf(f1[1]); s[6] = f2bf(f1[2]); s[7] = f2bf(f1[3]);
      *reinterpret_cast<short8*>(smem + rm_addr(0, row, c0 + 8 * j)) = s;
    }
  }
  __syncthreads();

  // ---- QKV GEMM: wave w computes head w's q,k,v (64 x 96 cols)
  // acc[mi][j]: j = 2*section + half; section 0=q 1=k 2=v
  f32x4 acc[4][6] = {};
  for (int ks = 0; ks < 8; ++ks) {
    int k0 = ks * 32;
    short8 a[4];
    for (int mi = 0; mi < 4; ++mi)
      a[mi] = *reinterpret_cast<const short8*>(
          smem + rm_addr(0, ll + 16 * mi, k0 + lg * 8));
    for (int j = 0; j < 6; ++j) {
      int s = j >> 1, hf = j & 1;
      int c = s * 256 + w * 32 + hf * 16 + ll;   // output column
      short8 bb = *reinterpret_cast<const short8*>(wqkv + c * 256 + k0 + lg * 8);
      for (int mi = 0; mi < 4; ++mi)
        acc[mi][j] = __builtin_amdgcn_mfma_f32_16x16x32_bf16(a[mi], bb, acc[mi][j], 0, 0, 0);
    }
  }
  // write q (scaled via W), k row-major swizzled; v transposed per head
  for (int j = 0; j < 6; ++j) {
    int s = j >> 1, hf = j & 1;
    int c = s * 256 + w * 32 + hf * 16 + ll;
    float bias = qkv_b[c];
    if (s == 0) bias *= scale;
    for (int mi = 0; mi < 4; ++mi) {
      for (int r = 0; r < 4; ++r) {
        int row = lg * 4 + r + 16 * mi;
        short bf = f2bf(acc[mi][j][r] + bias);
        if (s == 0) {
          *reinterpret_cast<short*>(smem + rm_addr(32768, row, w * 32 + hf * 16 + ll)) = bf;
        } else if (s == 1) {
          *reinterpret_cast<short*>(smem + rm_addr(65536, row, w * 32 + hf * 16 + ll)) = bf;
        } else {
          int d = hf * 16 + ll;  // 0..31
          int addr = 98304 + w * 4096 + d * 128 + ((row * 2) ^ ((d & 7) << 4));
          *reinterpret_cast<short*>(smem + addr) = bf;
        }
      }
    }
  }
  __syncthreads();

  // ---- S = q_scaled @ k^T  (64x64 per head), + rpb + mask
  f32x4 sa[4][4];
  {
    short8 aq[4], bk[4];
    for (int mi = 0; mi < 4; ++mi)
      aq[mi] = *reinterpret_cast<const short8*>(
          smem + rm_addr(32768, ll + 16 * mi, w * 32 + lg * 8));
    for (int ni = 0; ni < 4; ++ni)
      bk[ni] = *reinterpret_cast<const short8*>(
          smem + rm_addr(65536, ll + 16 * ni, w * 32 + lg * 8));
    f32x4 z{0.0f, 0.0f, 0.0f, 0.0f};
    for (int mi = 0; mi < 4; ++mi)
      for (int ni = 0; ni < 4; ++ni)
        sa[mi][ni] = __builtin_amdgcn_mfma_f32_16x16x32_bf16(aq[mi], bk[ni], z, 0, 0, 0);
    const float* rp = rpb + w * 4096;
    const float* mk = mask + (size_t)(b & 63) * 4096;
    for (int mi = 0; mi < 4; ++mi)
      for (int r = 0; r < 4; ++r) {
        int row = lg * 4 + r + 16 * mi;
        for (int ni = 0; ni < 4; ++ni) {
          int col = ll + 16 * ni;
          sa[mi][ni][r] += rp[row * 64 + col] + mk[row * 64 + col];
        }
      }
  }

  // ---- softmax over cols (row lives in one 16-lane group)
  float rinv[4][4];
  for (int mi = 0; mi < 4; ++mi)
    for (int r = 0; r < 4; ++r) {
      float m = sa[mi][0][r];
      for (int ni = 1; ni < 4; ++ni) m = fmaxf(m, sa[mi][ni][r]);
      for (int d = 1; d < 16; d <<= 1) m = fmaxf(m, __shfl_xor(m, d));
      float sum = 0.f;
      for (int ni = 0; ni < 4; ++ni) {
        float e = __expf(sa[mi][ni][r] - m);
        sa[mi][ni][r] = e;
        sum += e;
      }
      for (int d = 1; d < 16; d <<= 1) sum += __shfl_xor(sum, d);
      rinv[mi][r] = 1.0f / sum;
    }

  __syncthreads();  // all q reads done -> safe to overwrite x/q regions with P

  // ---- write P (unnormalized, bf16) to per-wave 8KB region in [x|q] space
  {
    int base = w * 8192;
    for (int mi = 0; mi < 4; ++mi)
      for (int ni = 0; ni < 4; ++ni)
        for (int r = 0; r < 4; ++r) {
          int row = lg * 4 + r + 16 * mi;
          int col = ll + 16 * ni;
          int addr = base + row * 128 + ((col * 2) ^ ((row & 7) << 4));
          *reinterpret_cast<short*>(smem + addr) = f2bf(sa[mi][ni][r]);
        }
  }
  __syncthreads();  // P visible

  // ---- out = P @ V  (V pre-transposed per head at 98304)
  f32x4 oa[4][2] = {};
  {
    int base = w * 8192;
    for (int ks = 0; ks < 2; ++ks) {
      short8 ap[4];
      for (int mi = 0; mi < 4; ++mi) {
        int row = ll + 16 * mi;
        int addr = base + row * 128 + (((ks * 32 + lg * 8) * 2) ^ ((row & 7) << 4));
        ap[mi] = *reinterpret_cast<const short8*>(smem + addr);
      }
      for (int nj = 0; nj < 2; ++nj) {
        int d = ll + 16 * nj;
        int addr = 98304 + w * 4096 + d * 128 + (((ks * 32 + lg * 8) * 2) ^ ((d & 7) << 4));
        short8 bv = *reinterpret_cast<const short8*>(smem + addr);
        for (int mi = 0; mi < 4; ++mi)
          oa[mi][nj] = __builtin_amdgcn_mfma_f32_16x16x32_bf16(ap[mi], bv, oa[mi][nj], 0, 0, 0);
      }
    }
  }
  // normalize rows, write attn output (bf16) into k region [64][256]
  for (int mi = 0; mi < 4; ++mi)
    for (int nj = 0; nj < 2; ++nj)
      for (int r = 0; r < 4; ++r) {
        int row = lg * 4 + r + 16 * mi;
        float v = oa[mi][nj][r] * rinv[mi][r];
        *reinterpret_cast<short*>(smem + rm_addr(65536, row, w * 32 + nj * 16 + ll)) = f2bf(v);
      }
  __syncthreads();

  // ---- proj GEMM: out[64][256] = attn[64][256] @ Wp^T + bias
  f32x4 pa[4][2] = {};
  for (int ks = 0; ks < 8; ++ks) {
    int k0 = ks * 32;
    short8 a[4];
    for (int mi = 0; mi < 4; ++mi)
      a[mi] = *reinterpret_cast<const short8*>(
          smem + rm_addr(65536, ll + 16 * mi, k0 + lg * 8));
    for (int nj = 0; nj < 2; ++nj) {
      int c = w * 32 + nj * 16 + ll;
      short8 bb = *reinterpret_cast<const short8*>(wproj + c * 256 + k0 + lg * 8);
      for (int mi = 0; mi < 4; ++mi)
        pa[mi][nj] = __builtin_amdgcn_mfma_f32_16x16x32_bf16(a[mi], bb, pa[mi][nj], 0, 0, 0);
    }
  }
  float* outp = out + (size_t)b * TOK * CDIM;
  for (int nj = 0; nj < 2; ++nj) {
    int c = w * 32 + nj * 16 + ll;
    float bias = proj_b[c];
    for (int mi = 0; mi < 4; ++mi)
      for (int r = 0; r < 4; ++r) {
        int row = lg * 4 + r + 16 * mi;
        outp[row * 256 + c] = pa[mi][nj][r] + bias;
      }
  }
}

extern "C" void kernel_launch(void* const* d_in, const int* in_sizes, int n_in,
                              void* d_out, int out_size, void* d_ws, size_t ws_size,
                              hipStream_t stream) {
  const float* x        = (const float*)d_in[0];
  const float* mask     = (const float*)d_in[1];
  const float* qkv_w    = (const float*)d_in[2];
  const float* qkv_b    = (const float*)d_in[3];
  const float* proj_w   = (const float*)d_in[4];
  const float* proj_b   = (const float*)d_in[5];
  const float* rpb_tab  = (const float*)d_in[6];
  const int*   rpb_idx  = (const int*)d_in[7];
  float* out = (float*)d_out;

  short* wqkv = (short*)d_ws;
  short* wproj = wqkv + 768 * 256;
  float* rpb_pre = (float*)(wproj + 256 * 256);

  int total = 768 * 256 + 256 * 256 + 8 * 64 * 64;
  preconv_kernel<<<(total + 255) / 256, 256, 0, stream>>>(
      qkv_w, proj_w, rpb_tab, rpb_idx, wqkv, wproj, rpb_pre);

  hipFuncSetAttribute((const void*)fused_attn,
                      hipFuncAttributeMaxDynamicSharedMemorySize, 131072);
  int B = in_sizes[0] / (TOK * CDIM);  // 2048
  fused_attn<<<B, 512, 131072, stream>>>(x, mask, qkv_b, proj_b, wqkv, wproj,
                                         rpb_pre, out);
}